// Round 1
// baseline (738.696 us; speedup 1.0000x reference)
//
#include <hip/hip_runtime.h>

// RoIAlign (legacy/caffe-style, aligned=False variant per reference):
//   features: (B=4, C=1024, H=64, W=64) fp32
//   rois:     (N=2048, 5) fp32  [batch, x1, y1, x2, y2] in image coords
//   out:      (N, C, 7, 7) fp32
//
// v2 strategy: the previous direct-gather version was limited by scattered
// 4B vector-memory transactions (~25 lines per wave-load, ~65% TCP busy),
// not HBM BW (46% of peak, VALU 12.7%). This version stages each roi's
// COMPACTED footprint (only the <=14 distinct rows {hs,hs+1} and <=8
// distinct 4-float col-quads containing {ws,ws+1}) into LDS with coalesced
// float4 loads, then does bilinear reads from LDS. Per-bin weights + LDS
// offsets are precomputed once per block; each compute thread owns a fixed
// bin so its params live in registers across all channels.

#define SCALE    0.0625f
#define C_       1024
#define H_       64
#define W_       64
#define HW       (H_ * W_)        // 4096
#define CHW      (C_ * HW)
#define AH_      7
#define AW_      7
#define NBIN     49               // 7*7
#define PER_ROI  (C_ * NBIN)      // 50176
#define QCH      256              // channels handled per block
#define CHUNK    8                // channels staged per iteration
#define RCAP     14               // max distinct rows: 7 ph values x {hs,hs+1} (structural)
#define QCAP     8                // max staged col-quads (data bound; fallback if exceeded)
#define CSPAN    36               // floats per row slot: >=4*QCAP, mult of 4, 36%32=4 spreads banks

__global__ __launch_bounds__(256, 8) void roialign_kernel(
    const float* __restrict__ feat,
    const float* __restrict__ rois,
    float* __restrict__ out)
{
    __shared__ __align__(16) float s_data[CHUNK][RCAP * CSPAN];  // 16128 B
    __shared__ float4 s_w[NBIN];     // corner weights (ul, ur, dl, dr)
    __shared__ int    s_hs[NBIN], s_ws[NBIN];
    __shared__ int    s_ul[NBIN], s_dl[NBIN];   // LDS float-offsets within a channel tile
    __shared__ int    s_goff[NBIN];  // hs*W + ws (fallback path)
    __shared__ int    s_rowG[RCAP];  // compacted slot -> global row
    __shared__ int    s_quadG[16];   // compacted slot -> global col-quad
    __shared__ unsigned long long s_rm;  // row bitmask (64 rows)
    __shared__ unsigned int       s_qm;  // quad bitmask (16 quads)
    __shared__ int    s_R, s_Q, s_b;

    const int n = blockIdx.x >> 2;   // roi index
    const int q = blockIdx.x & 3;    // channel-quarter index
    const int t = threadIdx.x;

    if (t < NBIN) {
        // Match numpy rounding exactly: no FMA contraction here, so floor()
        // boundary decisions agree with the reference bit-for-bit.
        #pragma clang fp contract(off)
        const float r0 = rois[n * 5 + 0];
        const float r1 = rois[n * 5 + 1];
        const float r2 = rois[n * 5 + 2];
        const float r3 = rois[n * 5 + 3];
        const float r4 = rois[n * 5 + 4];
        const int   b  = (int)r0;
        const float x1 = r1 * SCALE;
        const float y1 = r2 * SCALE;
        const float x2 = r3 * SCALE;
        const float y2 = r4 * SCALE;
        const float roi_w = fmaxf(x2 - x1, 0.0f);
        const float roi_h = fmaxf(y2 - y1, 0.0f);
        const float bin_w = roi_w / (float)(AW_ - 1);  // IEEE divide
        const float bin_h = roi_h / (float)(AH_ - 1);

        const int ph = t / AW_;
        const int pw = t - ph * AW_;

        const float h = y1 + (float)ph * bin_h;
        const float w = x1 + (float)pw * bin_w;

        const float hstart = fminf(floorf(h), (float)(H_ - 2));
        const float wstart = fminf(floorf(w), (float)(W_ - 2));
        const float hr = h - hstart;
        const float wr = w - wstart;

        const bool valid = (h >= 0.0f) && (h < (float)H_) &&
                           (w >= 0.0f) && (w < (float)W_);

        const int hs = min(max((int)hstart, 0), H_ - 2);
        const int ws = min(max((int)wstart, 0), W_ - 2);

        float wul = (1.0f - hr) * (1.0f - wr);
        float wur = (1.0f - hr) * wr;
        float wdl = hr * (1.0f - wr);
        float wdr = hr * wr;
        if (!valid) { wul = 0.0f; wur = 0.0f; wdl = 0.0f; wdr = 0.0f; }

        s_w[t]    = make_float4(wul, wur, wdl, wdr);
        s_hs[t]   = hs;
        s_ws[t]   = ws;
        s_goff[t] = hs * W_ + ws;
        if (t == 0) s_b = b;
    }
    __syncthreads();

    if (t == 0) {
        // Build row/quad occupancy masks and compacted slot->global tables.
        unsigned long long rm = 0ull;
        unsigned int       qm = 0u;
        for (int i = 0; i < NBIN; ++i) {
            rm |= 3ull << s_hs[i];                       // rows hs, hs+1
            const int w0 = s_ws[i];
            qm |= (1u << (w0 >> 2)) | (1u << ((w0 + 1) >> 2));
        }
        int R = 0;
        for (int r = 0; r < H_; ++r)
            if ((rm >> r) & 1ull) s_rowG[R++] = r;       // R <= 14 structurally
        int Qn = 0;
        for (int qq = 0; qq < 16; ++qq)
            if ((qm >> qq) & 1u) s_quadG[Qn++] = qq;     // Qn <= 14 structurally
        s_rm = rm; s_qm = qm; s_R = R; s_Q = Qn;
    }
    __syncthreads();

    const int R  = s_R;
    const int Qn = s_Q;
    const int rq = R * Qn;

    const float* featC = feat + (size_t)s_b * CHW + (size_t)(q * QCH) * HW;
    float*       ob    = out + (size_t)n * PER_ROI + (size_t)(q * QCH) * NBIN;

    if (Qn > QCAP || R > RCAP) {
        // General-case fallback: direct gather (previous kernel's loop).
        for (int e = t; e < QCH * NBIN; e += 256) {
            const unsigned eu  = (unsigned)e;
            const unsigned c   = eu / NBIN;        // magic-mul division
            const unsigned bin = eu - c * NBIN;
            const float4 wg  = s_w[bin];
            const int    off = s_goff[bin] + (int)(c << 12);
            const float ul = featC[off];
            const float ur = featC[off + 1];
            const float dl = featC[off + W_];
            const float dr = featC[off + W_ + 1];
            const float v = ul * wg.x + ur * wg.y + dl * wg.z + dr * wg.w;
            __builtin_nontemporal_store(v, ob + e);
        }
        return;
    }

    // Per-bin LDS offsets via compacted-slot arithmetic.
    if (t < NBIN) {
        const unsigned long long rm = s_rm;
        const unsigned int       qm = s_qm;
        const int hs = s_hs[t], ws = s_ws[t];
        // col index: 4*slot(quad(ws)) + (ws&3). ws+1 lands at colIdx+1 even
        // across a quad boundary because adjacent present quads get adjacent slots.
        const int colIdx = 4 * __popc(qm & ((1u << (ws >> 2)) - 1u)) + (ws & 3);
        const int rsu = __popcll(rm & ((1ull << hs) - 1ull));   // slot(hs)
        const int rsd = __popcll(rm & ((2ull << hs) - 1ull));   // slot(hs+1)
        s_ul[t] = rsu * CSPAN + colIdx;
        s_dl[t] = rsd * CSPAN + colIdx;
    }
    __syncthreads();

    // ---- per-thread load mapping (constant across all chunks) ----
    // rq <= RCAP*QCAP = 112, so chSpan >= 2.
    const int chSpan = 256 / rq;
    const int subCh  = t / rq;     // runtime div, once per block
    const int idx    = t % rq;
    const bool loadActive = (subCh < chSpan);
    int gOffT = 0, lOffT = 0;
    if (loadActive) {
        const int r_  = idx / Qn;  // runtime div, once per block
        const int sq_ = idx - r_ * Qn;
        gOffT = s_rowG[r_] * W_ + s_quadG[sq_] * 4;   // float offset in channel
        lOffT = r_ * CSPAN + sq_ * 4;                 // float offset in LDS tile
    }

    // ---- per-thread compute mapping: fixed bin, params in registers ----
    const int cl0 = t / NBIN;                 // compile-time magic div
    const int bin = t - cl0 * NBIN;
    const bool computeActive = (t < 5 * NBIN);  // 245 threads
    float4 w4 = make_float4(0.f, 0.f, 0.f, 0.f);
    int ulo = 0, dlo = 0;
    if (computeActive) { w4 = s_w[bin]; ulo = s_ul[bin]; dlo = s_dl[bin]; }

    for (int cc = 0; cc < QCH; cc += CHUNK) {
        // Stage CHUNK channels' compacted footprints (coalesced float4s).
        if (loadActive) {
            for (int ch = subCh; ch < CHUNK; ch += chSpan) {
                const float4 v = *(const float4*)(featC + (size_t)(cc + ch) * HW + gOffT);
                *(float4*)(&s_data[ch][lOffT]) = v;
            }
        }
        __syncthreads();

        if (computeActive) {
            for (int cl = cl0; cl < CHUNK; cl += 5) {
                const float* sd = s_data[cl];
                const float vul = sd[ulo];
                const float vur = sd[ulo + 1];
                const float vdl = sd[dlo];
                const float vdr = sd[dlo + 1];
                const float v = vul * w4.x + vur * w4.y + vdl * w4.z + vdr * w4.w;
                __builtin_nontemporal_store(v, ob + (cc + cl) * NBIN + bin);
            }
        }
        __syncthreads();
    }
}

extern "C" void kernel_launch(void* const* d_in, const int* in_sizes, int n_in,
                              void* d_out, int out_size, void* d_ws, size_t ws_size,
                              hipStream_t stream) {
    const float* feat = (const float*)d_in[0];
    const float* rois = (const float*)d_in[1];
    float* out = (float*)d_out;
    const int N = in_sizes[1] / 5;  // 2048
    dim3 grid(N * 4);
    dim3 block(256);
    roialign_kernel<<<grid, block, 0, stream>>>(feat, rois, out);
}

// Round 2
// 578.949 us; speedup vs baseline: 1.2759x; 1.2759x over previous
//
#include <hip/hip_runtime.h>

// RoIAlign (legacy/caffe-style, aligned=False variant per reference):
//   features: (B=4, C=1024, H=64, W=64) fp32
//   rois:     (N=2048, 5) fp32  [batch, x1, y1, x2, y2] in image coords
//   out:      (N, C, 7, 7) fp32
//
// v3 strategy: v1 (direct gather) and v2 (LDS-staged coalesced gather) both
// pinned at 3.7 TB/s with FETCH_SIZE ~1.0 GB vs 64 MB of unique feature
// data: 16x L2-miss amplification from zero cross-roi reuse. This version is
// channel-slice-major with an XCD-aware block swizzle: each XCD processes one
// 32-channel slice (32ch x 4batch x 16KB = 2 MB, fits the 4 MB private L2)
// against ALL 2048 rois before moving to its next slice. Each feature byte
// is fetched from HBM once machine-wide. Intra-block machinery (compacted
// row/quad footprint staged to LDS via coalesced float4s, per-bin params in
// registers) is carried over from v2.

#define SCALE    0.0625f
#define C_       1024
#define H_       64
#define W_       64
#define HW       (H_ * W_)        // 4096
#define CHW      (C_ * HW)
#define AH_      7
#define AW_      7
#define NBIN     49               // 7*7
#define PER_ROI  (C_ * NBIN)      // 50176
#define QCH      32               // channels handled per block (slice)
#define NSLICE   (C_ / QCH)       // 32
#define CHUNK    8                // channels staged per iteration
#define RCAP     14               // max distinct rows: 7 ph values x {hs,hs+1}
#define QCAP     8                // max staged col-quads (data bound; fallback if exceeded)
#define CSPAN    36               // floats per row slot: >=4*QCAP, mult of 4, 36%32=4 spreads banks
#define NXCD     8

__global__ __launch_bounds__(256, 8) void roialign_kernel(
    const float* __restrict__ feat,
    const float* __restrict__ rois,
    float* __restrict__ out,
    int N)
{
    __shared__ __align__(16) float s_data[CHUNK][RCAP * CSPAN];  // 16128 B
    __shared__ float4 s_w[NBIN];     // corner weights (ul, ur, dl, dr)
    __shared__ int    s_hs[NBIN], s_ws[NBIN];
    __shared__ int    s_ul[NBIN], s_dl[NBIN];   // LDS float-offsets within a channel tile
    __shared__ int    s_goff[NBIN];  // hs*W + ws (fallback path)
    __shared__ int    s_rowG[RCAP];  // compacted slot -> global row
    __shared__ int    s_quadG[16];   // compacted slot -> global col-quad
    __shared__ int    s_R, s_Q, s_b;

    // ---- XCD-aware decode: b = ((slice_sub*N + roi) << 3) | xcd ----
    // Consecutive blocks round-robin across XCDs (idx % 8 heuristic); with
    // slice_sub slowest, each XCD sees exactly one 2 MB channel-slice at a
    // time, swept across all rois -> slice stays L2-resident.
    const unsigned bidx = blockIdx.x;
    const int xcd       = (int)(bidx & (NXCD - 1));
    const unsigned tmp  = bidx >> 3;
    const int roi       = (int)(tmp % (unsigned)N);
    const int slice_sub = (int)(tmp / (unsigned)N);      // [0, NSLICE/NXCD)
    const int slice     = slice_sub * NXCD + xcd;        // [0, NSLICE)
    const int t = threadIdx.x;

    unsigned long long rm = 0ull;   // row occupancy mask (wave 0)
    unsigned int       qm = 0u;     // col-quad occupancy mask (wave 0)

    if (t < 64) {
        int hs = 0, ws = 0;
        if (t < NBIN) {
            // Match numpy rounding exactly: no FMA contraction here, so floor()
            // boundary decisions agree with the reference bit-for-bit.
            #pragma clang fp contract(off)
            const float r0 = rois[roi * 5 + 0];
            const float r1 = rois[roi * 5 + 1];
            const float r2 = rois[roi * 5 + 2];
            const float r3 = rois[roi * 5 + 3];
            const float r4 = rois[roi * 5 + 4];
            const int   b  = (int)r0;
            const float x1 = r1 * SCALE;
            const float y1 = r2 * SCALE;
            const float x2 = r3 * SCALE;
            const float y2 = r4 * SCALE;
            const float roi_w = fmaxf(x2 - x1, 0.0f);
            const float roi_h = fmaxf(y2 - y1, 0.0f);
            const float bin_w = roi_w / (float)(AW_ - 1);  // IEEE divide
            const float bin_h = roi_h / (float)(AH_ - 1);

            const int ph = t / AW_;
            const int pw = t - ph * AW_;

            const float h = y1 + (float)ph * bin_h;
            const float w = x1 + (float)pw * bin_w;

            const float hstart = fminf(floorf(h), (float)(H_ - 2));
            const float wstart = fminf(floorf(w), (float)(W_ - 2));
            const float hr = h - hstart;
            const float wr = w - wstart;

            const bool valid = (h >= 0.0f) && (h < (float)H_) &&
                               (w >= 0.0f) && (w < (float)W_);

            hs = min(max((int)hstart, 0), H_ - 2);
            ws = min(max((int)wstart, 0), W_ - 2);

            float wul = (1.0f - hr) * (1.0f - wr);
            float wur = (1.0f - hr) * wr;
            float wdl = hr * (1.0f - wr);
            float wdr = hr * wr;
            if (!valid) { wul = 0.0f; wur = 0.0f; wdl = 0.0f; wdr = 0.0f; }

            s_w[t]    = make_float4(wul, wur, wdl, wdr);
            s_hs[t]   = hs;
            s_ws[t]   = ws;
            s_goff[t] = hs * W_ + ws;
            if (t == 0) s_b = b;

            rm = 3ull << hs;                                   // rows hs, hs+1
            qm = (1u << (ws >> 2)) | (1u << ((ws + 1) >> 2));  // quads of ws, ws+1
        }

        // Wave-0 OR-reduction: all 64 lanes end with the full masks.
        #pragma unroll
        for (int d = 1; d < 64; d <<= 1) {
            rm |= __shfl_xor(rm, d);
            qm |= __shfl_xor(qm, d);
        }

        // Compacted slot -> global tables, built in parallel.
        if ((rm >> t) & 1ull)
            s_rowG[__popcll(rm & ((1ull << t) - 1ull))] = t;
        if (t < 16 && ((qm >> t) & 1u))
            s_quadG[__popc(qm & ((1u << t) - 1u))] = t;
        if (t == 0) { s_R = (int)__popcll(rm); s_Q = __popc(qm); }

        // Per-bin LDS offsets via compacted-slot arithmetic (masks in regs).
        if (t < NBIN) {
            // col index: 4*slot(quad(ws)) + (ws&3). ws+1 lands at colIdx+1 even
            // across a quad boundary because adjacent present quads get adjacent slots.
            const int colIdx = 4 * __popc(qm & ((1u << (ws >> 2)) - 1u)) + (ws & 3);
            const int rsu = __popcll(rm & ((1ull << hs) - 1ull));   // slot(hs)
            const int rsd = __popcll(rm & ((2ull << hs) - 1ull));   // slot(hs+1)
            s_ul[t] = rsu * CSPAN + colIdx;
            s_dl[t] = rsd * CSPAN + colIdx;
        }
    }
    __syncthreads();

    const int R  = s_R;
    const int Qn = s_Q;
    const int rq = R * Qn;

    const float* featC = feat + (size_t)s_b * CHW + (size_t)(slice * QCH) * HW;
    float*       ob    = out + (size_t)roi * PER_ROI + (size_t)(slice * QCH) * NBIN;

    if (Qn > QCAP || R > RCAP) {
        // General-case fallback: direct gather.
        for (int e = t; e < QCH * NBIN; e += 256) {
            const unsigned eu  = (unsigned)e;
            const unsigned c   = eu / NBIN;        // magic-mul division
            const unsigned bin = eu - c * NBIN;
            const float4 wg  = s_w[bin];
            const int    off = s_goff[bin] + (int)(c << 12);
            const float ul = featC[off];
            const float ur = featC[off + 1];
            const float dl = featC[off + W_];
            const float dr = featC[off + W_ + 1];
            const float v = ul * wg.x + ur * wg.y + dl * wg.z + dr * wg.w;
            __builtin_nontemporal_store(v, ob + e);
        }
        return;
    }

    // ---- per-thread load mapping (constant across all chunks) ----
    // rq <= RCAP*QCAP = 112, so chSpan >= 2.
    const int chSpan = 256 / rq;
    const int subCh  = t / rq;     // runtime div, once per block
    const int idx    = t % rq;
    const bool loadActive = (subCh < chSpan);
    int gOffT = 0, lOffT = 0;
    if (loadActive) {
        const int r_  = idx / Qn;  // runtime div, once per block
        const int sq_ = idx - r_ * Qn;
        gOffT = s_rowG[r_] * W_ + s_quadG[sq_] * 4;   // float offset in channel
        lOffT = r_ * CSPAN + sq_ * 4;                 // float offset in LDS tile
    }

    // ---- per-thread compute mapping: fixed bin, params in registers ----
    const int cl0 = t / NBIN;                 // compile-time magic div
    const int bin = t - cl0 * NBIN;
    const bool computeActive = (t < 5 * NBIN);  // 245 threads
    float4 w4 = make_float4(0.f, 0.f, 0.f, 0.f);
    int ulo = 0, dlo = 0;
    if (computeActive) { w4 = s_w[bin]; ulo = s_ul[bin]; dlo = s_dl[bin]; }

    for (int cc = 0; cc < QCH; cc += CHUNK) {
        // Stage CHUNK channels' compacted footprints (coalesced float4s,
        // L2-resident after the first roi touches this slice).
        if (loadActive) {
            for (int ch = subCh; ch < CHUNK; ch += chSpan) {
                const float4 v = *(const float4*)(featC + (cc + ch) * HW + gOffT);
                *(float4*)(&s_data[ch][lOffT]) = v;
            }
        }
        __syncthreads();

        if (computeActive) {
            for (int cl = cl0; cl < CHUNK; cl += 5) {
                const float* sd = s_data[cl];
                const float vul = sd[ulo];
                const float vur = sd[ulo + 1];
                const float vdl = sd[dlo];
                const float vdr = sd[dlo + 1];
                const float v = vul * w4.x + vur * w4.y + vdl * w4.z + vdr * w4.w;
                __builtin_nontemporal_store(v, ob + (cc + cl) * NBIN + bin);
            }
        }
        __syncthreads();
    }
}

extern "C" void kernel_launch(void* const* d_in, const int* in_sizes, int n_in,
                              void* d_out, int out_size, void* d_ws, size_t ws_size,
                              hipStream_t stream) {
    const float* feat = (const float*)d_in[0];
    const float* rois = (const float*)d_in[1];
    float* out = (float*)d_out;
    const int N = in_sizes[1] / 5;  // 2048
    dim3 grid((unsigned)N * NSLICE);
    dim3 block(256);
    roialign_kernel<<<grid, block, 0, stream>>>(feat, rois, out, N);
}